// Round 1
// baseline (119.749 us; speedup 1.0000x reference)
//
#include <hip/hip_runtime.h>

// AttentionLSTM_13529146983094
//
// Key observation: the reference applies layer_norm over a dimension of SIZE 1
// right before the final projection:
//     h = layer_norm(h, ln2_g, ln2_b)   # h: [B,S,1]
// mean over a size-1 axis == the element itself, var == 0, so the normalized
// value is exactly 0*g + b = ln2_b[0] for EVERY element — everything upstream
// (both LSTM stacks, attention, MLP) is annihilated. Hence:
//     out[b, o] = ln2_b[0] * sum_s Wf[o, s] + bf[o]
// which is the same 30-vector broadcast to all 8192 batch rows.
//
// Kernel: compute the 30 constants once per block (trivial), then broadcast-
// write 8192x30 fp32 (983 KB) with float4 stores. Memory/launch-overhead bound.

#define B_SZ    8192
#define SEQ_L   90
#define OUTL    30

// total floats = 8192*30 = 245760 ; /4 = 61440 float4 stores
// 240 blocks x 256 threads = 61440 threads, one float4 each.

__global__ __launch_bounds__(256) void attn_lstm_const_bcast(
        const float* __restrict__ Wf,     // [30, 90]
        const float* __restrict__ bf,     // [30]
        const float* __restrict__ ln2_b,  // [1]
        float* __restrict__ out)          // [8192, 30]
{
    __shared__ float vals[OUTL];
    const int t = threadIdx.x;
    if (t < OUTL) {
        float s = 0.f;
        const float* row = Wf + t * SEQ_L;
        #pragma unroll
        for (int j = 0; j < SEQ_L; ++j) s += row[j];
        vals[t] = fmaf(ln2_b[0], s, bf[t]);   // = bf[t] exactly when ln2_b==0
    }
    __syncthreads();

    const int gid  = blockIdx.x * blockDim.x + threadIdx.x;  // 0..61439
    const int base = gid * 4;                                 // float index
    float4 v;
    v.x = vals[(base + 0) % OUTL];
    v.y = vals[(base + 1) % OUTL];
    v.z = vals[(base + 2) % OUTL];
    v.w = vals[(base + 3) % OUTL];
    reinterpret_cast<float4*>(out)[gid] = v;
}

extern "C" void kernel_launch(void* const* d_in, const int* in_sizes, int n_in,
                              void* d_out, int out_size, void* d_ws, size_t ws_size,
                              hipStream_t stream) {
    // setup_inputs() order:
    //  0: x
    //  1..12 : enc (Wih,Whh,bih,bhh) x 3 layers
    // 13..24 : dec (Wih,Whh,bih,bhh) x 3 layers
    // 25: ln_g  26: ln_b
    // 27: W1    28: b1   29: W2   30: b2
    // 31: ln2_g 32: ln2_b
    // 33: Wf    34: bf
    const float* Wf    = (const float*)d_in[33];
    const float* bf    = (const float*)d_in[34];
    const float* ln2_b = (const float*)d_in[32];
    float* out = (float*)d_out;

    const int total_f4 = (B_SZ * OUTL) / 4;      // 61440
    const int threads  = 256;
    const int blocks   = total_f4 / threads;     // 240

    attn_lstm_const_bcast<<<blocks, threads, 0, stream>>>(Wf, bf, ln2_b, out);
}